// Round 7
// baseline (460.150 us; speedup 1.0000x reference)
//
#include <hip/hip_runtime.h>
#include <hip/hip_bf16.h>

#define NIN    512
#define NEVAL  1536
#define NCOLS  2048
#define NOUT   256
#define OUT_BASE 1280
#define NBLK   48       // NEVAL / 32

typedef __attribute__((ext_vector_type(8))) short short8;   // 8 bf16 (4 VGPRs)
typedef __attribute__((ext_vector_type(4))) float floatx4;  // MFMA C/D

// ---------- helpers ----------

__device__ __forceinline__ unsigned short f2bf(float f) {
    __hip_bfloat16 h = __float2bfloat16(f);
    return __builtin_bit_cast(unsigned short, h);
}
__device__ __forceinline__ unsigned pack2(float a, float b) {
    return (unsigned)f2bf(a) | ((unsigned)f2bf(b) << 16);
}
// sigmoid(clip(5z,-60,60)): clamp dropped — v_exp overflow gives exact 0/1.
__device__ __forceinline__ float sigmoid5(float z) {
    return __builtin_amdgcn_rcpf(1.0f + __expf(-5.0f * z));
}

// ---------- W fp32 -> bf16 (d_ws re-poisoned every launch, so rerun) ----------

__global__ __launch_bounds__(256) void wconv(const float* __restrict__ W,
                                             ushort* __restrict__ Wb, int n8) {
    int i = blockIdx.x * blockDim.x + threadIdx.x;
    if (i < n8) {
        float4 v0 = ((const float4*)W)[2 * i];
        float4 v1 = ((const float4*)W)[2 * i + 1];
        uint4 pk;
        pk.x = pack2(v0.x, v0.y); pk.y = pack2(v0.z, v0.w);
        pk.z = pack2(v1.x, v1.y); pk.w = pack2(v1.z, v1.w);
        ((uint4*)Wb)[i] = pk;
    }
}

// ---------- main kernel ----------
// 256 WGs x 1024 threads (16 waves). WG owns 16 batch rows; wave w owns row w.
// O[16][2048] bf16 in LDS, row r rotated by 8r elements (b128-aligned swizzle).
// Per 32-node block k (columns [L0, L0+32), L0 = 512+32k):
//   tail:  one K=32 MFMA over [L0-32, L0), gated to owning K-split slot
//   Zred:  16 waves' partials (2 node-halves x 8 K-splits) -> LDS -> gather
//   main:  MFMAs for block k+1 over [0, L0) issued before the chain
//   chain: 32 sequential steps, readlane broadcast
// ROUND-7 FIX: R6 showed VGPR_Count=40 — the compiler SINKS the const W
// loads into the chain (legal: W never aliased), putting a ~300-500cyc
// global load on every serial step = the invariant ~395us. Pin the 32
// weights into VGPRs with an empty asm "+v" barrier placed after the
// gather: the load latency is covered by tail+Zred+barrierB+gather, and
// the chain becomes register-only.

__global__ __launch_bounds__(1024) void ffnet(const float* __restrict__ x,
                                              const float* __restrict__ W,
                                              const ushort* __restrict__ Wb,
                                              const float* __restrict__ bias,
                                              float* __restrict__ out) {
    __shared__ unsigned short O[16 * 2048];   // 64 KB
    __shared__ float Zred[16 * 256];          // 16 KB  [wave][lane][reg]

    const int t    = threadIdx.x;
    const int w    = t >> 6;        // wave 0..15
    const int lane = t & 63;

    // phase-A role
    const int m16  = lane & 15;     // A row (batch row) / D col (node)
    const int quad = lane >> 4;     // 0..3
    const int half = w >> 3;        // 0..1
    const int ksp  = w & 7;         // 0..7
    const int arow = m16 << 11;
    const int arot = m16 << 3;

    // chain role: wave w owns local row w; lanes 32-63 mirror lanes 0-31
    const int ii   = lane & 31;
    const long row = (long)blockIdx.x * 16 + w;
    const int rot  = w << 3;

    // ---- stage x row w into LDS as bf16 (swizzled) ----
    {
        const float* xr = x + row * NIN + lane * 8;
        float4 v0 = *(const float4*)xr;
        float4 v1 = *(const float4*)(xr + 4);
        uint4 pk;
        pk.x = pack2(v0.x, v0.y); pk.y = pack2(v0.z, v0.w);
        pk.z = pack2(v1.x, v1.y); pk.w = pack2(v1.z, v1.w);
        *(uint4*)&O[(w << 11) + ((lane * 8 + rot) & 2047)] = pk;
    }
    __syncthreads();

    // ---- prologue: main(0) over columns [0, 480) ----
    floatx4 acc = {0.f, 0.f, 0.f, 0.f};
    {
        const ushort* wb = Wb + (size_t)(half * 16 + m16) * NCOLS;
        for (int kk = ksp * 32; kk < NIN - 32; kk += 256) {
            short8 a = *(const short8*)&O[arow + ((kk + quad * 8 + arot) & 2047)];
            short8 b = *(const short8*)&wb[kk + quad * 8];
            acc = __builtin_amdgcn_mfma_f32_16x16x32_bf16(a, b, acc, 0, 0, 0);
        }
    }

    for (int k = 0; k < NBLK; ++k) {
        const int i0 = k << 5;
        const int L0 = NIN + i0;
        const int g  = i0 + ii;     // this lane's eval-node index (mirrored)

        __syncthreads();            // barrier A: chain(k-1) O-writes visible

        // issue diag-weight + bias loads (consumed after the pin below)
        const float* wd = W + (size_t)g * NCOLS + L0;
        float4 a0 = *(const float4*)(wd +  0);
        float4 a1 = *(const float4*)(wd +  4);
        float4 a2 = *(const float4*)(wd +  8);
        float4 a3 = *(const float4*)(wd + 12);
        float4 a4 = *(const float4*)(wd + 16);
        float4 a5 = *(const float4*)(wd + 20);
        float4 a6 = *(const float4*)(wd + 24);
        float4 a7 = *(const float4*)(wd + 28);
        float bi = bias[g];
        float w00 = a0.x, w01 = a0.y, w02 = a0.z, w03 = a0.w;
        float w04 = a1.x, w05 = a1.y, w06 = a1.z, w07 = a1.w;
        float w08 = a2.x, w09 = a2.y, w10 = a2.z, w11 = a2.w;
        float w12 = a3.x, w13 = a3.y, w14 = a3.z, w15 = a3.w;
        float w16 = a4.x, w17 = a4.y, w18 = a4.z, w19 = a4.w;
        float w20 = a5.x, w21 = a5.y, w22 = a5.z, w23 = a5.w;
        float w24 = a6.x, w25 = a6.y, w26 = a6.z, w27 = a6.w;
        float w28 = a7.x, w29 = a7.y, w30 = a7.z, w31 = a7.w;

        // tail: K=32 MFMA over [L0-32, L0) — chunk 15+k, owner ksp=(k+7)&7
        if (ksp == ((k + 7) & 7)) {
            const ushort* wb = Wb + (size_t)(i0 + half * 16 + m16) * NCOLS;
            const int ts = L0 - 32;
            short8 a = *(const short8*)&O[arow + ((ts + quad * 8 + arot) & 2047)];
            short8 b = *(const short8*)&wb[ts + quad * 8];
            acc = __builtin_amdgcn_mfma_f32_16x16x32_bf16(a, b, acc, 0, 0, 0);
        }

        // D frag: lane q*16+n holds Z[m=4q+reg][n]
        *(floatx4*)&Zred[(w << 8) + (lane << 2)] = acc;
        __syncthreads();            // barrier B

        // gather z for (row w, node ii): sum 8 K-split partials
        const int h = ii >> 4, n = ii & 15;
        const int ridx = ((w >> 2) << 6) + (n << 2) + (w & 3);
        float zacc = bi;
        #pragma unroll
        for (int p = 0; p < 8; ++p)
            zacc += Zred[(((h << 3) + p) << 8) + ridx];

        // PIN the 32 weights into VGPRs here — forbids sinking the loads
        // into the serial chain (R2..R6's hidden limiter).
        asm volatile("" : "+v"(w00), "+v"(w01), "+v"(w02), "+v"(w03),
                          "+v"(w04), "+v"(w05), "+v"(w06), "+v"(w07));
        asm volatile("" : "+v"(w08), "+v"(w09), "+v"(w10), "+v"(w11),
                          "+v"(w12), "+v"(w13), "+v"(w14), "+v"(w15));
        asm volatile("" : "+v"(w16), "+v"(w17), "+v"(w18), "+v"(w19),
                          "+v"(w20), "+v"(w21), "+v"(w22), "+v"(w23));
        asm volatile("" : "+v"(w24), "+v"(w25), "+v"(w26), "+v"(w27),
                          "+v"(w28), "+v"(w29), "+v"(w30), "+v"(w31));

        // issue main(k+1) over [0, L0)
        floatx4 accN = {0.f, 0.f, 0.f, 0.f};
        if (k + 1 < NBLK) {
            const ushort* wb = Wb + (size_t)(i0 + 32 + half * 16 + m16) * NCOLS;
            #pragma unroll 2
            for (int kk = ksp * 32; kk < L0; kk += 256) {
                short8 a = *(const short8*)&O[arow + ((kk + quad * 8 + arot) & 2047)];
                short8 b = *(const short8*)&wb[kk + quad * 8];
                accN = __builtin_amdgcn_mfma_f32_16x16x32_bf16(a, b, accN, 0, 0, 0);
            }
        }

        // chain: 32 sequential sigmoid steps — register-only serial path.
        #define CH(JJ, WDC)                                                    \
            {                                                                  \
                float zj = __builtin_bit_cast(float,                           \
                    __builtin_amdgcn_readlane(                                 \
                        __builtin_bit_cast(int, zacc), JJ));                   \
                zacc = fmaf(WDC, sigmoid5(zj), zacc);                          \
            }
        CH( 0, w00) CH( 1, w01) CH( 2, w02) CH( 3, w03)
        CH( 4, w04) CH( 5, w05) CH( 6, w06) CH( 7, w07)
        CH( 8, w08) CH( 9, w09) CH(10, w10) CH(11, w11)
        CH(12, w12) CH(13, w13) CH(14, w14) CH(15, w15)
        CH(16, w16) CH(17, w17) CH(18, w18) CH(19, w19)
        CH(20, w20) CH(21, w21) CH(22, w22) CH(23, w23)
        CH(24, w24) CH(25, w25) CH(26, w26) CH(27, w27)
        CH(28, w28) CH(29, w29) CH(30, w30) CH(31, w31)
        #undef CH
        float o = sigmoid5(zacc);

        if (lane < 32) {
            O[(w << 11) + ((L0 + ii + rot) & 2047)] = f2bf(o);
            if (g >= OUT_BASE)
                out[row * NOUT + (g - OUT_BASE)] = o;
        }
        acc = accN;
    }
}

// ---------- launch ----------

extern "C" void kernel_launch(void* const* d_in, const int* in_sizes, int n_in,
                              void* d_out, int out_size, void* d_ws, size_t ws_size,
                              hipStream_t stream) {
    const float* x  = (const float*)d_in[0];   // [4096, 512]
    const float* W  = (const float*)d_in[1];   // [1536, 2048]
    const float* b  = (const float*)d_in[2];   // [1536]
    float* out = (float*)d_out;                // [4096, 256]
    ushort* Wb = (ushort*)d_ws;                // bf16 W copy (6.3 MB)

    int n8 = NEVAL * NCOLS / 8;
    wconv<<<n8 / 256, 256, 0, stream>>>(W, Wb, n8);
    ffnet<<<4096 / 16, 1024, 0, stream>>>(x, W, Wb, b, out);
}

// Round 8
// 305.924 us; speedup vs baseline: 1.5041x; 1.5041x over previous
//
#include <hip/hip_runtime.h>
#include <hip/hip_bf16.h>

#define NIN    512
#define NEVAL  1536
#define NCOLS  2048
#define NOUT   256
#define OUT_BASE 1280
#define NBLK   48       // NEVAL / 32

typedef __attribute__((ext_vector_type(8))) short short8;   // 8 bf16 (4 VGPRs)
typedef __attribute__((ext_vector_type(4))) float floatx4;  // MFMA C/D

// ---------- helpers ----------

__device__ __forceinline__ unsigned short f2bf(float f) {
    __hip_bfloat16 h = __float2bfloat16(f);
    return __builtin_bit_cast(unsigned short, h);
}
__device__ __forceinline__ unsigned pack2(float a, float b) {
    return (unsigned)f2bf(a) | ((unsigned)f2bf(b) << 16);
}
// sigmoid(clip(5z,-60,60)): clamp dropped — v_exp overflow gives exact 0/1.
__device__ __forceinline__ float sigmoid5(float z) {
    return __builtin_amdgcn_rcpf(1.0f + __expf(-5.0f * z));
}

// ---------- W fp32 -> bf16 (d_ws re-poisoned every launch, so rerun) ----------

__global__ __launch_bounds__(256) void wconv(const float* __restrict__ W,
                                             ushort* __restrict__ Wb, int n8) {
    int i = blockIdx.x * blockDim.x + threadIdx.x;
    if (i < n8) {
        float4 v0 = ((const float4*)W)[2 * i];
        float4 v1 = ((const float4*)W)[2 * i + 1];
        uint4 pk;
        pk.x = pack2(v0.x, v0.y); pk.y = pack2(v0.z, v0.w);
        pk.z = pack2(v1.x, v1.y); pk.w = pack2(v1.z, v1.w);
        ((uint4*)Wb)[i] = pk;
    }
}

// ---------- main kernel ----------
// 256 WGs x 1024 threads (16 waves). WG owns 16 batch rows; wave w owns row w.
// O[16][2048] bf16 in LDS, row r rotated by 8r elements (b128-aligned swizzle).
// Per 32-node block k (columns [L0, L0+32), L0 = 512+32k):
//   stage: diag block W[i0..i0+32)[L0..L0+32) -> Wd LDS (stride 33), one
//          float per thread — the block is SHARED by all 16 waves (each wave
//          chains the same triangle for its own batch row), so stage once.
//          Race-free: chain(k-1) reads Wd before barrier A; writes after it;
//          chain(k) reads after barrier B.
//   tail:  one K=32 MFMA over [L0-32, L0), gated to owning K-split slot
//   Zred:  16 waves' partials (2 node-halves x 8 K-splits) -> LDS -> gather
//   main:  MFMAs for block k+1 over [0, L0) issued before the chain
//   chain: 32 sequential steps, readlane broadcast; weight = ds_read from
//          Wd[ii*33+jj] (stride 33 -> column reads conflict-free; addresses
//          known upfront so the compiler can prefetch ahead of the chain).
// ROUND-8: R2-R7 invariant ~397us across register/global/scratch weight
// media; LDS is the remaining medium and removes the allocator from the
// picture (VGPR_Count=40 was too small to hold 32 weights in any round).

__global__ __launch_bounds__(1024) void ffnet(const float* __restrict__ x,
                                              const float* __restrict__ W,
                                              const ushort* __restrict__ Wb,
                                              const float* __restrict__ bias,
                                              float* __restrict__ out) {
    __shared__ unsigned short O[16 * 2048];   // 64 KB
    __shared__ float Zred[16 * 256];          // 16 KB  [wave][lane][reg]
    __shared__ float Wd[32 * 33];             // 4.2 KB diag block, stride 33

    const int t    = threadIdx.x;
    const int w    = t >> 6;        // wave 0..15
    const int lane = t & 63;

    // phase-A role
    const int m16  = lane & 15;     // A row (batch row) / D col (node)
    const int quad = lane >> 4;     // 0..3
    const int half = w >> 3;        // 0..1
    const int ksp  = w & 7;         // 0..7
    const int arow = m16 << 11;
    const int arot = m16 << 3;

    // chain role: wave w owns local row w; lanes 32-63 mirror lanes 0-31
    const int ii   = lane & 31;
    const long row = (long)blockIdx.x * 16 + w;
    const int rot  = w << 3;

    // staging role: one float of the diag block per thread
    const int sn = t >> 5;          // 0..31 (node within block)
    const int sc = t & 31;          // 0..31 (col within block)

    // ---- stage x row w into LDS as bf16 (swizzled) ----
    {
        const float* xr = x + row * NIN + lane * 8;
        float4 v0 = *(const float4*)xr;
        float4 v1 = *(const float4*)(xr + 4);
        uint4 pk;
        pk.x = pack2(v0.x, v0.y); pk.y = pack2(v0.z, v0.w);
        pk.z = pack2(v1.x, v1.y); pk.w = pack2(v1.z, v1.w);
        *(uint4*)&O[(w << 11) + ((lane * 8 + rot) & 2047)] = pk;
    }
    __syncthreads();

    // ---- prologue: main(0) over columns [0, 480) ----
    floatx4 acc = {0.f, 0.f, 0.f, 0.f};
    {
        const ushort* wb = Wb + (size_t)(half * 16 + m16) * NCOLS;
        for (int kk = ksp * 32; kk < NIN - 32; kk += 256) {
            short8 a = *(const short8*)&O[arow + ((kk + quad * 8 + arot) & 2047)];
            short8 b = *(const short8*)&wb[kk + quad * 8];
            acc = __builtin_amdgcn_mfma_f32_16x16x32_bf16(a, b, acc, 0, 0, 0);
        }
    }

    for (int k = 0; k < NBLK; ++k) {
        const int i0 = k << 5;
        const int L0 = NIN + i0;
        const int g  = i0 + ii;     // this lane's eval-node index (mirrored)

        __syncthreads();            // barrier A: chain(k-1) O/Wd-reads done

        // stage this block's 32x32 diag weights into LDS (shared by all waves)
        Wd[sn * 33 + sc] = W[(size_t)(i0 + sn) * NCOLS + L0 + sc];
        float bi = bias[g];

        // tail: K=32 MFMA over [L0-32, L0) — chunk 15+k, owner ksp=(k+7)&7
        if (ksp == ((k + 7) & 7)) {
            const ushort* wb = Wb + (size_t)(i0 + half * 16 + m16) * NCOLS;
            const int ts = L0 - 32;
            short8 a = *(const short8*)&O[arow + ((ts + quad * 8 + arot) & 2047)];
            short8 b = *(const short8*)&wb[ts + quad * 8];
            acc = __builtin_amdgcn_mfma_f32_16x16x32_bf16(a, b, acc, 0, 0, 0);
        }

        // D frag: lane q*16+n holds Z[m=4q+reg][n]
        *(floatx4*)&Zred[(w << 8) + (lane << 2)] = acc;
        __syncthreads();            // barrier B: Zred + Wd visible

        // gather z for (row w, node ii): sum 8 K-split partials
        const int h = ii >> 4, n = ii & 15;
        const int ridx = ((w >> 2) << 6) + (n << 2) + (w & 3);
        float zacc = bi;
        #pragma unroll
        for (int p = 0; p < 8; ++p)
            zacc += Zred[(((h << 3) + p) << 8) + ridx];

        // issue main(k+1) over [0, L0)
        floatx4 accN = {0.f, 0.f, 0.f, 0.f};
        if (k + 1 < NBLK) {
            const ushort* wb = Wb + (size_t)(i0 + 32 + half * 16 + m16) * NCOLS;
            #pragma unroll 2
            for (int kk = ksp * 32; kk < L0; kk += 256) {
                short8 a = *(const short8*)&O[arow + ((kk + quad * 8 + arot) & 2047)];
                short8 b = *(const short8*)&wb[kk + quad * 8];
                accN = __builtin_amdgcn_mfma_f32_16x16x32_bf16(a, b, accN, 0, 0, 0);
            }
        }

        // chain: 32 sequential sigmoid steps; weight from LDS (addresses
        // independent of chain values -> prefetchable by the scheduler).
        #pragma unroll
        for (int jj = 0; jj < 32; ++jj) {
            float zj = __builtin_bit_cast(float,
                __builtin_amdgcn_readlane(__builtin_bit_cast(int, zacc), jj));
            float wji = Wd[ii * 33 + jj];
            zacc = fmaf(wji, sigmoid5(zj), zacc);
        }
        float o = sigmoid5(zacc);

        if (lane < 32) {
            O[(w << 11) + ((L0 + ii + rot) & 2047)] = f2bf(o);
            if (g >= OUT_BASE)
                out[row * NOUT + (g - OUT_BASE)] = o;
        }
        acc = accN;
    }
}

// ---------- launch ----------

extern "C" void kernel_launch(void* const* d_in, const int* in_sizes, int n_in,
                              void* d_out, int out_size, void* d_ws, size_t ws_size,
                              hipStream_t stream) {
    const float* x  = (const float*)d_in[0];   // [4096, 512]
    const float* W  = (const float*)d_in[1];   // [1536, 2048]
    const float* b  = (const float*)d_in[2];   // [1536]
    float* out = (float*)d_out;                // [4096, 256]
    ushort* Wb = (ushort*)d_ws;                // bf16 W copy (6.3 MB)

    int n8 = NEVAL * NCOLS / 8;
    wconv<<<n8 / 256, 256, 0, stream>>>(W, Wb, n8);
    ffnet<<<4096 / 16, 1024, 0, stream>>>(x, W, Wb, b, out);
}